// Round 12
// baseline (573.504 us; speedup 1.0000x reference)
//
#include <hip/hip_runtime.h>
#include <hip/hip_fp16.h>
#include <math.h>

#define N_NODES 50000
#define N_EDGES 1600000
#define HID 256
#define SCAN_B 196   // ceil(N_NODES/256)
// eps = 0

typedef _Float16 f16x8 __attribute__((ext_vector_type(8)));
typedef float f32x4 __attribute__((ext_vector_type(4)));
typedef float v2f __attribute__((ext_vector_type(2)));

// ROCm 7.2 has no __hmax2 — emit v_pk_max_f16 directly.
static __device__ __forceinline__ __half2 pk_max2(__half2 a, __half2 b) {
    unsigned au = *reinterpret_cast<unsigned*>(&a);
    unsigned bu = *reinterpret_cast<unsigned*>(&b);
    unsigned r;
    asm("v_pk_max_f16 %0, %1, %2" : "=v"(r) : "v"(au), "v"(bu));
    return *reinterpret_cast<__half2*>(&r);
}

// 4 floats -> 4 fp8 (e4m3) packed in one dword
static __device__ __forceinline__ unsigned pack4_fp8(float a, float b, float c, float d) {
    int v = __builtin_amdgcn_cvt_pk_fp8_f32(a, b, 0, false);
    v = __builtin_amdgcn_cvt_pk_fp8_f32(c, d, v, true);
    return (unsigned)v;
}

// ---------------------------------------------------------------- CSR build ---
// 4 edges per thread (strided).
__global__ __launch_bounds__(256) void hist_kernel(const int* __restrict__ dst,
                                                   int* __restrict__ deg) {
    const int T = gridDim.x * 256;
    const int t = blockIdx.x * 256 + threadIdx.x;
#pragma unroll
    for (int i = 0; i < 4; ++i) {
        int e = t + i * T;
        if (e < N_EDGES) atomicAdd(&deg[dst[e]], 1);   // fire & forget
    }
}

__global__ __launch_bounds__(256) void scan1_kernel(const int* __restrict__ deg,
                                                    int* __restrict__ bsum) {
    int idx = blockIdx.x * 256 + threadIdx.x;
    int v = (idx < N_NODES) ? deg[idx] : 0;
#pragma unroll
    for (int off = 32; off > 0; off >>= 1) v += __shfl_down(v, off);
    __shared__ int ws[4];
    if ((threadIdx.x & 63) == 0) ws[threadIdx.x >> 6] = v;
    __syncthreads();
    if (threadIdx.x == 0) bsum[blockIdx.x] = ws[0] + ws[1] + ws[2] + ws[3];
}

__global__ __launch_bounds__(256) void scan2_kernel(int* __restrict__ bsum) {
    __shared__ int s[256];
    int t = threadIdx.x;
    int v = (t < SCAN_B) ? bsum[t] : 0;
    s[t] = v;
    __syncthreads();
    for (int off = 1; off < 256; off <<= 1) {
        int u = (t >= off) ? s[t - off] : 0;
        __syncthreads();
        s[t] += u;
        __syncthreads();
    }
    if (t < SCAN_B) bsum[t] = s[t] - v;  // exclusive
}

__global__ __launch_bounds__(256) void scan3_kernel(const int* __restrict__ deg,
                                                    const int* __restrict__ bsum,
                                                    int* __restrict__ base) {
    __shared__ int s[256];
    int t = threadIdx.x;
    int idx = blockIdx.x * 256 + t;
    int v = (idx < N_NODES) ? deg[idx] : 0;
    s[t] = v;
    __syncthreads();
    for (int off = 1; off < 256; off <<= 1) {
        int u = (t >= off) ? s[t - off] : 0;
        __syncthreads();
        s[t] += u;
        __syncthreads();
    }
    if (idx < N_NODES) base[idx] = bsum[blockIdx.x] + s[t] - v;
    if (idx == 0) base[N_NODES] = N_EDGES;
}

// permutation scatter: ONLY a 4 B random write per edge (was 32 B record).
__global__ __launch_bounds__(256) void scatter_perm_kernel(
        const int* __restrict__ dst,
        const int* __restrict__ base,
        int* __restrict__ cursor,
        int* __restrict__ perm) {
    const int T = gridDim.x * 256;
    const int t = blockIdx.x * 256 + threadIdx.x;
    const int e0 = t, e1 = t + T, e2 = t + 2 * T, e3 = t + 3 * T;
    const bool v3 = (e3 < N_EDGES);
    int d0 = dst[e0], d1 = dst[e1], d2 = dst[e2];
    int d3 = v3 ? dst[e3] : 0;
    int p0 = base[d0] + atomicAdd(&cursor[d0], 1);
    int p1 = base[d1] + atomicAdd(&cursor[d1], 1);
    int p2 = base[d2] + atomicAdd(&cursor[d2], 1);
    int p3 = v3 ? (base[d3] + atomicAdd(&cursor[d3], 1)) : 0;
    perm[p0] = e0;
    perm[p1] = e1;
    perm[p2] = e2;
    if (v3) perm[p3] = e3;
}

// ---------------------------------------------------------------- layer 1 ---
// Fused: record build (gather ea/src via perm, SEQUENTIAL record write) +
// layer-1 gather-MLP. One wave per node; writes h as fp8.
__global__ __launch_bounds__(256) void layer1_kernel(
        const float* __restrict__ x,     // [N][2]
        const float* __restrict__ ea,    // [E][7] raw fp32
        const int* __restrict__ src,     // [E]
        const int* __restrict__ perm,    // [E] dst-sorted edge ids
        const int* __restrict__ base,    // [N+1]
        const float* __restrict__ We1,   // [7][2]
        const float* __restrict__ be1,   // [2]
        const float* __restrict__ W1,    // [2][256]
        const float* __restrict__ b1,    // [256]
        float* __restrict__ rec,         // [E][8] out: {dup half2 x7, src}
        unsigned* __restrict__ h8) {     // [N][64] dwords (fp8 x4)
    const int lane = threadIdx.x & 63;
    const int wid = threadIdx.x >> 6;
    const int n = blockIdx.x * 4 + wid;
    if (n >= N_NODES) return;
    float w00 = We1[0],  w01 = We1[1],  w10 = We1[2],  w11 = We1[3];
    float w20 = We1[4],  w21 = We1[5],  w30 = We1[6],  w31 = We1[7];
    float w40 = We1[8],  w41 = We1[9],  w50 = We1[10], w51 = We1[11];
    float w60 = We1[12], w61 = We1[13];
    float bb0 = be1[0], bb1 = be1[1];
    float m0 = 0.f, m1 = 0.f;
    const int s0 = base[n], s1 = base[n + 1];
    for (int pos = s0 + lane; pos < s1; pos += 64) {
        int e = perm[pos];                       // coalesced
        const float* ep = ea + (size_t)e * 7;    // random read (L2/L3)
        float a0 = ep[0], a1 = ep[1], a2 = ep[2], a3 = ep[3];
        float a4 = ep[4], a5 = ep[5], a6 = ep[6];
        int s = src[e];                          // random 4B read
        // ---- build packed record (sequential 32 B write)
        float4 v0, v1;
        *(__half2*)&v0.x = __floats2half2_rn(a0, a0);
        *(__half2*)&v0.y = __floats2half2_rn(a1, a1);
        *(__half2*)&v0.z = __floats2half2_rn(a2, a2);
        *(__half2*)&v0.w = __floats2half2_rn(a3, a3);
        *(__half2*)&v1.x = __floats2half2_rn(a4, a4);
        *(__half2*)&v1.y = __floats2half2_rn(a5, a5);
        *(__half2*)&v1.z = __floats2half2_rn(a6, a6);
        v1.w = __int_as_float(s);
        float* rp = rec + (size_t)pos * 8;
        *(float4*)rp       = v0;
        *(float4*)(rp + 4) = v1;
        // ---- layer-1 message (fp32 math on raw ea)
        float t0 = bb0, t1 = bb1;
        t0 = fmaf(a0, w00, t0); t1 = fmaf(a0, w01, t1);
        t0 = fmaf(a1, w10, t0); t1 = fmaf(a1, w11, t1);
        t0 = fmaf(a2, w20, t0); t1 = fmaf(a2, w21, t1);
        t0 = fmaf(a3, w30, t0); t1 = fmaf(a3, w31, t1);
        t0 = fmaf(a4, w40, t0); t1 = fmaf(a4, w41, t1);
        t0 = fmaf(a5, w50, t0); t1 = fmaf(a5, w51, t1);
        t0 = fmaf(a6, w60, t0); t1 = fmaf(a6, w61, t1);
        float2 xv = *(const float2*)&x[(size_t)s * 2];
        m0 += fmaxf(t0 + xv.x, 0.f);
        m1 += fmaxf(t1 + xv.y, 0.f);
    }
#pragma unroll
    for (int off = 32; off > 0; off >>= 1) {
        m0 += __shfl_down(m0, off);
        m1 += __shfl_down(m1, off);
    }
    m0 = __shfl(m0, 0);
    m1 = __shfl(m1, 0);
    const float t0 = x[n * 2 + 0] + m0;
    const float t1 = x[n * 2 + 1] + m1;
    const int c = lane * 4;
    float4 wa = *(const float4*)&W1[c];
    float4 wb = *(const float4*)&W1[256 + c];
    float4 bv = *(const float4*)&b1[c];
    float4 r;
    r.x = fmaxf(fmaf(t0, wa.x, fmaf(t1, wb.x, bv.x)), 0.f);
    r.y = fmaxf(fmaf(t0, wa.y, fmaf(t1, wb.y, bv.y)), 0.f);
    r.z = fmaxf(fmaf(t0, wa.z, fmaf(t1, wb.z, bv.z)), 0.f);
    r.w = fmaxf(fmaf(t0, wa.w, fmaf(t1, wb.w, bv.w)), 0.f);
    h8[(size_t)n * 64 + lane] = pack4_fp8(r.x, r.y, r.z, r.w);
}

// ------------------------------------------------------------ layers 2..3 ---
// CSR gather from fp8 h (1 dword = 4 channels/lane), packed-fp16 edge MLP,
// fp16 accumulate. One wave/node; ping-pong, 4 edges/group, 8 h-loads in flight.
#define EDGEH(RA, RB, HU)                                              \
    do {                                                               \
        __half2 _a0 = *(__half2*)&RA.x, _a1 = *(__half2*)&RA.y;        \
        __half2 _a2 = *(__half2*)&RA.z, _a3 = *(__half2*)&RA.w;        \
        __half2 _a4 = *(__half2*)&RB.x, _a5 = *(__half2*)&RB.y;        \
        __half2 _a6 = *(__half2*)&RB.z;                                \
        __half2 _m0 = bb01, _m1 = bb23;                                \
        _m0 = __hfma2(_a0, w0a, _m0); _m1 = __hfma2(_a0, w0b, _m1);    \
        _m0 = __hfma2(_a1, w1a, _m0); _m1 = __hfma2(_a1, w1b, _m1);    \
        _m0 = __hfma2(_a2, w2a, _m0); _m1 = __hfma2(_a2, w2b, _m1);    \
        _m0 = __hfma2(_a3, w3a, _m0); _m1 = __hfma2(_a3, w3b, _m1);    \
        _m0 = __hfma2(_a4, w4a, _m0); _m1 = __hfma2(_a4, w4b, _m1);    \
        _m0 = __hfma2(_a5, w5a, _m0); _m1 = __hfma2(_a5, w5b, _m1);    \
        _m0 = __hfma2(_a6, w6a, _m0); _m1 = __hfma2(_a6, w6b, _m1);    \
        v2f _hf0 = __builtin_amdgcn_cvt_pk_f32_fp8((int)(HU), false);  \
        v2f _hf1 = __builtin_amdgcn_cvt_pk_f32_fp8((int)(HU), true);   \
        __half2 _h0 = __float22half2_rn(make_float2(_hf0.x, _hf0.y));  \
        __half2 _h1 = __float22half2_rn(make_float2(_hf1.x, _hf1.y));  \
        _m0 = pk_max2(__hadd2(_m0, _h0), z2);                          \
        _m1 = pk_max2(__hadd2(_m1, _h1), z2);                          \
        acc0 = __hadd2(acc0, _m0);                                     \
        acc1 = __hadd2(acc1, _m1);                                     \
    } while (0)

#define HLOAD(RB) (h8[(size_t)__builtin_amdgcn_readfirstlane(          \
                       __float_as_int(RB.w)) * 64 + lane])

#define LOADG(A0, B0, A1, B1, A2, B2, A3, B3, H0, H1, H2, H3, G)       \
    do {                                                               \
        const float4* _rp = rp + (size_t)(G) * 8;                      \
        A0 = _rp[0]; B0 = _rp[1]; A1 = _rp[2]; B1 = _rp[3];            \
        A2 = _rp[4]; B2 = _rp[5]; A3 = _rp[6]; B3 = _rp[7];            \
        H0 = HLOAD(B0); H1 = HLOAD(B1);                                \
        H2 = HLOAD(B2); H3 = HLOAD(B3);                                \
    } while (0)

#define CONS4(A0, B0, A1, B1, A2, B2, A3, B3, H0, H1, H2, H3)          \
    do {                                                               \
        EDGEH(A0, B0, H0); EDGEH(A1, B1, H1);                          \
        EDGEH(A2, B2, H2); EDGEH(A3, B3, H3);                          \
    } while (0)

__global__ __launch_bounds__(256) void aggr2_kernel(
        const unsigned* __restrict__ h8,  // [N][64] dwords (fp8 x4)
        const float* __restrict__ rec,    // [E][8] dst-sorted packed records
        const int* __restrict__ base,     // [N+1]
        const float* __restrict__ We2,    // [7][256] fp32
        const float* __restrict__ be2,    // [256] fp32
        __half* __restrict__ accum) {     // [N][256] fp16 out
    const int lane = threadIdx.x & 63;
    const int n = blockIdx.x * 4 + (threadIdx.x >> 6);
    if (n >= N_NODES) return;
    const int c4 = lane * 4;
    __half2 w0a = __floats2half2_rn(We2[0 * HID + c4], We2[0 * HID + c4 + 1]);
    __half2 w0b = __floats2half2_rn(We2[0 * HID + c4 + 2], We2[0 * HID + c4 + 3]);
    __half2 w1a = __floats2half2_rn(We2[1 * HID + c4], We2[1 * HID + c4 + 1]);
    __half2 w1b = __floats2half2_rn(We2[1 * HID + c4 + 2], We2[1 * HID + c4 + 3]);
    __half2 w2a = __floats2half2_rn(We2[2 * HID + c4], We2[2 * HID + c4 + 1]);
    __half2 w2b = __floats2half2_rn(We2[2 * HID + c4 + 2], We2[2 * HID + c4 + 3]);
    __half2 w3a = __floats2half2_rn(We2[3 * HID + c4], We2[3 * HID + c4 + 1]);
    __half2 w3b = __floats2half2_rn(We2[3 * HID + c4 + 2], We2[3 * HID + c4 + 3]);
    __half2 w4a = __floats2half2_rn(We2[4 * HID + c4], We2[4 * HID + c4 + 1]);
    __half2 w4b = __floats2half2_rn(We2[4 * HID + c4 + 2], We2[4 * HID + c4 + 3]);
    __half2 w5a = __floats2half2_rn(We2[5 * HID + c4], We2[5 * HID + c4 + 1]);
    __half2 w5b = __floats2half2_rn(We2[5 * HID + c4 + 2], We2[5 * HID + c4 + 3]);
    __half2 w6a = __floats2half2_rn(We2[6 * HID + c4], We2[6 * HID + c4 + 1]);
    __half2 w6b = __floats2half2_rn(We2[6 * HID + c4 + 2], We2[6 * HID + c4 + 3]);
    __half2 bb01 = __floats2half2_rn(be2[c4], be2[c4 + 1]);
    __half2 bb23 = __floats2half2_rn(be2[c4 + 2], be2[c4 + 3]);
    const __half2 z2 = __float2half2_rn(0.f);

    // acc init = h[n] (fp8 -> fp16)
    __half2 acc0, acc1;
    {
        unsigned hv = h8[(size_t)n * 64 + lane];
        v2f f0 = __builtin_amdgcn_cvt_pk_f32_fp8((int)hv, false);
        v2f f1 = __builtin_amdgcn_cvt_pk_f32_fp8((int)hv, true);
        acc0 = __float22half2_rn(make_float2(f0.x, f0.y));
        acc1 = __float22half2_rn(make_float2(f1.x, f1.y));
    }
    const int s0 = __builtin_amdgcn_readfirstlane(base[n]);
    const int deg = __builtin_amdgcn_readfirstlane(base[n + 1]) - s0;
    const float4* rp = (const float4*)rec + (size_t)s0 * 2;
    const int ng = deg >> 2;

    float4 r0a, r0b, r1a, r1b, r2a, r2b, r3a, r3b;
    unsigned rh0, rh1, rh2, rh3;
    float4 t0a, t0b, t1a, t1b, t2a, t2b, t3a, t3b;
    unsigned th0, th1, th2, th3;

    if (ng > 0) {
        LOADG(r0a, r0b, r1a, r1b, r2a, r2b, r3a, r3b, rh0, rh1, rh2, rh3, 0);
        int g = 1;
        for (; g + 1 < ng; g += 2) {
            LOADG(t0a, t0b, t1a, t1b, t2a, t2b, t3a, t3b, th0, th1, th2, th3, g);
            CONS4(r0a, r0b, r1a, r1b, r2a, r2b, r3a, r3b, rh0, rh1, rh2, rh3);
            LOADG(r0a, r0b, r1a, r1b, r2a, r2b, r3a, r3b, rh0, rh1, rh2, rh3, g + 1);
            CONS4(t0a, t0b, t1a, t1b, t2a, t2b, t3a, t3b, th0, th1, th2, th3);
        }
        if (g < ng) {
            LOADG(t0a, t0b, t1a, t1b, t2a, t2b, t3a, t3b, th0, th1, th2, th3, g);
            CONS4(r0a, r0b, r1a, r1b, r2a, r2b, r3a, r3b, rh0, rh1, rh2, rh3);
            CONS4(t0a, t0b, t1a, t1b, t2a, t2b, t3a, t3b, th0, th1, th2, th3);
        } else {
            CONS4(r0a, r0b, r1a, r1b, r2a, r2b, r3a, r3b, rh0, rh1, rh2, rh3);
        }
    }
    for (int i = ng * 4; i < deg; ++i) {   // remainder 0..3 edges
        float4 ra = rp[(size_t)i * 2], rbv = rp[(size_t)i * 2 + 1];
        unsigned hv = HLOAD(rbv);
        EDGEH(ra, rbv, hv);
    }
    float2 of;
    *(__half2*)&of.x = acc0;
    *(__half2*)&of.y = acc1;
    *(float2*)&accum[(size_t)n * HID + c4] = of;
}

// ------------------------------------------------- W2 -> fp16 B-frag swizzle ---
// W2s[((ct*8+kc)*64+lane)*8 + j] = W2[kc*32 + (lane>>4)*8 + j][ct*16 + (lane&15)]
__global__ __launch_bounds__(256) void w2_swizzle_kernel(const float* __restrict__ W,
                                                         __half* __restrict__ W2s) {
    int t = blockIdx.x * 256 + threadIdx.x;   // 16*8*64 = 8192
    if (t >= 16 * 8 * 64) return;
    int lane = t & 63;
    int kc = (t >> 6) & 7;
    int ct = t >> 9;
    int k0 = kc * 32 + (lane >> 4) * 8;
    int col = ct * 16 + (lane & 15);
#pragma unroll
    for (int j = 0; j < 8; ++j)
        W2s[(size_t)t * 8 + j] = __float2half(W[(size_t)(k0 + j) * HID + col]);
}

// ---------------------------------------------------------------- node MLP ---
// relu(A @ W2 + b2) via mfma_f32_16x16x32_f16.
// FUSE_END=false: write h as fp8. FUSE_END=true: fuse the sigmoid head.
template <bool FUSE_END>
__global__ __launch_bounds__(256) void node2_mfma_kernel(
        const __half* __restrict__ A,     // [N][256] fp16 (accum)
        const __half* __restrict__ W2s,   // swizzled B-frags
        const float* __restrict__ b,      // [256]
        unsigned char* __restrict__ h8,   // [N][256] fp8 out (!FUSE_END)
        const float* __restrict__ Wend,   // [256] (FUSE_END)
        const float* __restrict__ bend,   // [1]   (FUSE_END)
        float* __restrict__ out) {        // [N] (FUSE_END)
    const int lane = threadIdx.x & 63;
    const int wv = threadIdx.x >> 6;
    const int n_base = blockIdx.x * 64 + wv * 16;
    if (n_base >= N_NODES) return;
    const int quad = lane >> 4;
    const int mrow = lane & 15;
    // A-frags for all 8 k-chunks: A[m=lane&15][k=quad*8+j]
    f16x8 af[8];
    const __half* ap = A + (size_t)(n_base + mrow) * HID + quad * 8;
#pragma unroll
    for (int kc = 0; kc < 8; ++kc)
        af[kc] = *(const f16x8*)(ap + kc * 32);
    float p0 = 0.f, p1 = 0.f, p2 = 0.f, p3 = 0.f;   // head partials (FUSE_END)
#pragma unroll
    for (int ct = 0; ct < 16; ++ct) {
        f32x4 c = {0.f, 0.f, 0.f, 0.f};
        const f16x8* bp = (const f16x8*)W2s + (size_t)(ct * 8) * 64 + lane;
#pragma unroll
        for (int kc = 0; kc < 8; ++kc)
            c = __builtin_amdgcn_mfma_f32_16x16x32_f16(af[kc], bp[(size_t)kc * 64],
                                                       c, 0, 0, 0);
        const int col = ct * 16 + mrow;            // D col = lane&15
        const float bias = b[col];
        if (!FUSE_END) {
#pragma unroll
            for (int r = 0; r < 4; ++r) {          // D row = quad*4 + r
                int n = n_base + quad * 4 + r;
                float v = fmaxf(c[r] + bias, 0.f);
                int pk = __builtin_amdgcn_cvt_pk_fp8_f32(v, v, 0, false);
                if (n < N_NODES)
                    h8[(size_t)n * HID + col] = (unsigned char)(pk & 0xff);
            }
        } else {
            const float we = Wend[col];
            p0 = fmaf(fmaxf(c[0] + bias, 0.f), we, p0);
            p1 = fmaf(fmaxf(c[1] + bias, 0.f), we, p1);
            p2 = fmaf(fmaxf(c[2] + bias, 0.f), we, p2);
            p3 = fmaf(fmaxf(c[3] + bias, 0.f), we, p3);
        }
    }
    if (FUSE_END) {
        // reduce over the 16 mrow lanes of each quad group
#pragma unroll
        for (int mask = 1; mask < 16; mask <<= 1) {
            p0 += __shfl_xor(p0, mask);
            p1 += __shfl_xor(p1, mask);
            p2 += __shfl_xor(p2, mask);
            p3 += __shfl_xor(p3, mask);
        }
        if (mrow == 0) {
            const float bd = bend[0];
            int n = n_base + quad * 4;
            if (n + 0 < N_NODES) out[n + 0] = 1.f / (1.f + expf(-(p0 + bd)));
            if (n + 1 < N_NODES) out[n + 1] = 1.f / (1.f + expf(-(p1 + bd)));
            if (n + 2 < N_NODES) out[n + 2] = 1.f / (1.f + expf(-(p2 + bd)));
            if (n + 3 < N_NODES) out[n + 3] = 1.f / (1.f + expf(-(p3 + bd)));
        }
    }
}

// ------------------------------------------------------------------ launch ---
extern "C" void kernel_launch(void* const* d_in, const int* in_sizes, int n_in,
                              void* d_out, int out_size, void* d_ws, size_t ws_size,
                              hipStream_t stream) {
    const float* x    = (const float*)d_in[0];
    const int*   ei   = (const int*)d_in[1];
    const float* ea   = (const float*)d_in[2];
    const float* We1  = (const float*)d_in[3];
    const float* be1  = (const float*)d_in[4];
    const float* W1   = (const float*)d_in[5];
    const float* b1   = (const float*)d_in[6];
    const float* We2  = (const float*)d_in[7];
    const float* be2  = (const float*)d_in[8];
    const float* W2   = (const float*)d_in[9];
    const float* b2   = (const float*)d_in[10];
    const float* Wend = (const float*)d_in[11];
    const float* bend = (const float*)d_in[12];
    float* out = (float*)d_out;

    const int* src = ei;
    const int* dst = ei + N_EDGES;

    const size_t HN = (size_t)N_NODES * HID;           // 12.8M elements
    __half*   Bh   = (__half*)d_ws;                    // [N][256] fp16 accum
    unsigned* Ah   = (unsigned*)(Bh + HN);             // [N][64] fp8x4 h
    float*    rec  = (float*)(Ah + (size_t)N_NODES * 64); // [E][8]
    int*      perm = (int*)(rec + (size_t)N_EDGES * 8);   // [E]
    __half*   W2s  = (__half*)(perm + N_EDGES);
    int*   deg    = (int*)(W2s + 16 * 8 * 64 * 8);     // [N]
    int*   cursor = deg + N_NODES;                     // [N]
    int*   base   = cursor + N_NODES;                  // [N+2]
    int*   bsum   = base + N_NODES + 2;                // [256]
    // total ≈ 97 MB

    const int E4_B = (N_EDGES + 4 * 256 - 1) / (4 * 256);   // 1563

    // ---- CSR build: histogram, scan, 4 B permutation scatter
    hipMemsetAsync(deg, 0, (size_t)N_NODES * 2 * sizeof(int), stream);  // deg+cursor
    hist_kernel<<<E4_B, 256, 0, stream>>>(dst, deg);
    scan1_kernel<<<SCAN_B, 256, 0, stream>>>(deg, bsum);
    scan2_kernel<<<1, 256, 0, stream>>>(bsum);
    scan3_kernel<<<SCAN_B, 256, 0, stream>>>(deg, bsum, base);
    scatter_perm_kernel<<<E4_B, 256, 0, stream>>>(dst, base, cursor, perm);
    w2_swizzle_kernel<<<32, 256, 0, stream>>>(W2, W2s);

    // ---- layer 1: record build (sequential writes) + gather-MLP -> Ah (fp8)
    layer1_kernel<<<(N_NODES + 3) / 4, 256, 0, stream>>>(x, ea, src, perm, base,
                                                         We1, be1, W1, b1, rec, Ah);

    const int N2_B = (N_NODES + 63) / 64;
    // ---- layer 2
    aggr2_kernel<<<(N_NODES + 3) / 4, 256, 0, stream>>>(Ah, rec, base, We2, be2, Bh);
    node2_mfma_kernel<false><<<N2_B, 256, 0, stream>>>(Bh, W2s, b2,
                                                       (unsigned char*)Ah,
                                                       nullptr, nullptr, nullptr);
    // ---- layer 3 + fused head
    aggr2_kernel<<<(N_NODES + 3) / 4, 256, 0, stream>>>(Ah, rec, base, We2, be2, Bh);
    node2_mfma_kernel<true><<<N2_B, 256, 0, stream>>>(Bh, W2s, b2, nullptr,
                                                      Wend, bend, out);
}